// Round 1
// 1100.312 us; speedup vs baseline: 1.1720x; 1.1720x over previous
//
#include <hip/hip_runtime.h>
#include <hip/hip_bf16.h>

#define BB 8
#define SS 4096
#define DD 64
#define QT 64
#define KTILE 128
#define NKT (SS / KTILE)      // 32
#define NTHREADS 512

typedef __attribute__((ext_vector_type(4))) short short4v;
typedef __attribute__((ext_vector_type(8))) short short8v;
typedef __attribute__((ext_vector_type(4))) float float4v;

__device__ __forceinline__ unsigned short f2bf(float f) {
  union { __hip_bfloat16 b; unsigned short u; } cv;
  cv.b = __float2bfloat16(f);
  return cv.u;
}

__device__ __forceinline__ short8v load8(const unsigned short* p) {
  union { short4v h[2]; short8v v; } u;
  u.h[0] = *(const short4v*)p;
  u.h[1] = *(const short4v*)(p + 4);
  return u.v;
}

// v2: occupancy 1 -> 2 blocks/CU.
//  - per-lane mask bits moved LDS -> 16 VGPRs via a one-time gather; the 33 KB Bm
//    region is then overlaid (Pool union) with Vt+Ps, cutting LDS 96256 -> 62976 B.
//  - __launch_bounds__(512,4) => 2 workgroups/CU (16 waves/CU, was 8).
//  - deletes ~1024 ds_read_b64/thread of Bm traffic from the two sweeps.
__global__ __launch_bounds__(NTHREADS, 4)
void attn_fused_kernel(const float* __restrict__ Q, const float* __restrict__ K,
                       const float* __restrict__ V, const int* __restrict__ M,
                       float* __restrict__ Octx, float* __restrict__ Oattn) {
  __shared__ __align__(16) unsigned short Qs[QT][72];        // [q][d], pad->72   (9216 B)
  __shared__ __align__(16) unsigned short Ks[KTILE][72];     // [kk][d]          (18432 B)
  // Pool: phase0 = Bm bitmask [QT*65] u64 (33280 B); sweep2 = Vt[64][136] + Ps[64][136] (34816 B)
  __shared__ __align__(16) unsigned char Pool[(DD + QT) * (KTILE + 8) * 2];
  __shared__ float RowSum[QT];
  __shared__ float InvRow[QT];

  unsigned long long* Bm = (unsigned long long*)Pool;        // row stride 65 u64
  typedef unsigned short PRow[KTILE + 8];                    // stride 136 shorts
  PRow* Vt = (PRow*)Pool;                                    // [DD][136] transposed V
  PRow* Ps = (PRow*)(Pool + (size_t)DD * (KTILE + 8) * 2);   // [QT][136] bf16 P

  const int tid  = threadIdx.x;
  const int w    = tid >> 6;
  const int lane = tid & 63;
  const int quad = lane >> 4;
  const int l15  = lane & 15;
  const int qs   = (w & 3) << 4;  // q-strip base (16 rows) for this wave
  const int kh   = (w >> 2) << 6; // kk half (0 or 64) for QK
  const int dh   = (w >> 2) << 5; // d half (0 or 32) for PV

  // batch-per-XCD swizzle: batch pinned to one XCD so its K+V (2 MB) stays in 4 MB L2
  const int bb = blockIdx.x & 7;
  const int qt = blockIdx.x >> 3;
  const int q0 = qt * QT;

  const float* Qg = Q + ((size_t)bb * SS + q0) * DD;
  const float* Kg = K + (size_t)bb * SS * DD;
  const float* Vg = V + (size_t)bb * SS * DD;
  const int*   Mg = M + ((size_t)bb * SS + q0) * (size_t)SS;
  float* Ag = Oattn + ((size_t)bb * SS + q0) * (size_t)SS;
  float* Cg = Octx + ((size_t)bb * SS + q0) * DD;

  if (tid < QT) RowSum[tid] = 0.f;

  // ---- Q tile -> LDS (bf16) ----
  for (int i = tid; i < QT * 16; i += NTHREADS) {
    const int r = i >> 4, c4 = (i & 15) << 2;
    const float4 qv = *(const float4*)(Qg + (size_t)r * DD + c4);
    short4v pk;
    pk.x = (short)f2bf(qv.x); pk.y = (short)f2bf(qv.y);
    pk.z = (short)f2bf(qv.z); pk.w = (short)f2bf(qv.w);
    *(short4v*)&Qs[r][c4] = pk;
  }

  // ---- mask -> LDS bitmask (single coalesced HBM read of the mask) ----
  // word layout: Bm[row*65 + (c>>8)*4 + (c&3)], bit index (c>>2)&63
  for (int it = w; it < QT * 16; it += 8) {
    const int r = it >> 4, g = it & 15;
    const int4 m4 = *(const int4*)(Mg + (size_t)r * SS + g * 256 + lane * 4);
    const unsigned long long b0 = __ballot(m4.x != 0);
    const unsigned long long b1 = __ballot(m4.y != 0);
    const unsigned long long b2 = __ballot(m4.z != 0);
    const unsigned long long b3 = __ballot(m4.w != 0);
    if (lane == 0) {
      unsigned long long* dst = &Bm[r * 65 + (g << 2)];
      dst[0] = b0; dst[1] = b1; dst[2] = b2; dst[3] = b3;
    }
  }
  __syncthreads();

  // persistent A-fragments (Q rows for this wave's strip)
  const short8v aq0 = load8(&Qs[qs + l15][quad * 8]);
  const short8v aq1 = load8(&Qs[qs + l15][32 + quad * 8]);

  // ---- one-time gather: this lane's 512 mask bits -> 16 VGPRs ----
  // column c = kt*128 + kh + t*16 + l15 lives in word Bm[row*65 + (kt>>1)*4 + (l15&3)]
  // at bit (kt&1)*32 + (kh>>2) + 4t + (l15>>2).  After >>B0 the 8 bits of a word sit at
  // {0,4,8,12} (kt even) and {32,36,40,44} (kt odd); compact each nibble-stride group
  // with the (x&0x1111)*0x1248>>12 gather.  Register bit layout:
  //   mreg[r][kt>>4] bit ((kt2>>1)<<3 | (kt2&1)<<2 | t),  kt2 = kt&15.
  const int B0 = (kh >> 2) + (l15 >> 2);
  unsigned long long mreg[4][2];
#pragma unroll
  for (int r = 0; r < 4; ++r) {
    const int row = qs + quad * 4 + r;
#pragma unroll
    for (int h = 0; h < 2; ++h) {
      unsigned long long acc = 0ULL;
#pragma unroll
      for (int g8 = 0; g8 < 8; ++g8) {
        const int w16 = h * 8 + g8;
        const unsigned long long W = Bm[row * 65 + w16 * 4 + (l15 & 3)] >> B0;
        const unsigned nl = ((((unsigned)W & 0x1111u) * 0x1248u) >> 12) & 0xFu;
        const unsigned nh = ((((unsigned)(W >> 32) & 0x1111u) * 0x1248u) >> 12) & 0xFu;
        acc |= (unsigned long long)(nl | (nh << 4)) << (g8 * 8);
      }
      mreg[r][h] = acc;
    }
  }
  // Bm is dead from here on; Pool is re-used as Vt/Ps in sweep 2 (barriers in
  // sweep 1 guarantee all gathers complete long before the first Vt/Ps write).

  // ================= sweep 1: row sums =================
  float rsum[4] = {0.f, 0.f, 0.f, 0.f};
#pragma unroll
  for (int half = 0; half < 2; ++half) {
    for (int kt2 = 0; kt2 < 16; ++kt2) {
      const int kt = (half << 4) | kt2;
      for (int i = tid; i < KTILE * 16; i += NTHREADS) {
        const int r = i >> 4, c4 = (i & 15) << 2;
        const float4 kv = *(const float4*)(Kg + (size_t)(kt * KTILE + r) * DD + c4);
        short4v pk;
        pk.x = (short)f2bf(kv.x); pk.y = (short)f2bf(kv.y);
        pk.z = (short)f2bf(kv.z); pk.w = (short)f2bf(kv.w);
        *(short4v*)&Ks[r][c4] = pk;
      }
      __syncthreads();
#pragma unroll
      for (int t = 0; t < 4; ++t) {
        float4v acc = {0.f, 0.f, 0.f, 0.f};
        const unsigned short* kp = &Ks[kh + t * 16 + l15][quad * 8];
        const short8v b0 = load8(kp);
        const short8v b1 = load8(kp + 32);
        acc = __builtin_amdgcn_mfma_f32_16x16x32_bf16(aq0, b0, acc, 0, 0, 0);
        acc = __builtin_amdgcn_mfma_f32_16x16x32_bf16(aq1, b1, acc, 0, 0, 0);
        const int bsh = ((kt2 >> 1) << 3) | ((kt2 & 1) << 2) | t;
#pragma unroll
        for (int r = 0; r < 4; ++r) {
          const bool msk = (mreg[r][half] >> bsh) & 1ULL;
          const float p = msk ? 0.f : __expf(acc[r] * 0.125f);
          rsum[r] += p;
        }
      }
      __syncthreads();
    }
  }

  // reduce row sums: 16 lanes (l15) share each row; 2 waves share a row -> LDS atomic
#pragma unroll
  for (int r = 0; r < 4; ++r) {
    float v = rsum[r];
    v += __shfl_xor(v, 1);
    v += __shfl_xor(v, 2);
    v += __shfl_xor(v, 4);
    v += __shfl_xor(v, 8);
    if (l15 == 0) atomicAdd(&RowSum[qs + quad * 4 + r], v);
  }
  __syncthreads();
  if (tid < QT) {
    const float s = RowSum[tid];
    InvRow[tid] = (s != 0.f) ? 1.f / s : 0.f;
  }
  __syncthreads();
  float inv[4];
#pragma unroll
  for (int r = 0; r < 4; ++r) inv[r] = InvRow[qs + quad * 4 + r];

  // ================= sweep 2: attn write + PV =================
  float4v cacc0 = {0.f, 0.f, 0.f, 0.f}, cacc1 = {0.f, 0.f, 0.f, 0.f};
#pragma unroll
  for (int half = 0; half < 2; ++half) {
    for (int kt2 = 0; kt2 < 16; ++kt2) {
      const int kt = (half << 4) | kt2;
      for (int i = tid; i < KTILE * 16; i += NTHREADS) {
        const int r = i >> 4, c4 = (i & 15) << 2;
        const float4 kv = *(const float4*)(Kg + (size_t)(kt * KTILE + r) * DD + c4);
        short4v pk;
        pk.x = (short)f2bf(kv.x); pk.y = (short)f2bf(kv.y);
        pk.z = (short)f2bf(kv.z); pk.w = (short)f2bf(kv.w);
        *(short4v*)&Ks[r][c4] = pk;
      }
      {
        // V tile, stored transposed Vt[d][kk]; per-lane 64B-sequential global reads (L2-resident)
        const int kk = tid & 127;
        const int d0 = (tid >> 7) << 4;
#pragma unroll
        for (int c4 = 0; c4 < 4; ++c4) {
          const float4 vv = *(const float4*)(Vg + (size_t)(kt * KTILE + kk) * DD + d0 + c4 * 4);
          Vt[d0 + c4 * 4 + 0][kk] = f2bf(vv.x);
          Vt[d0 + c4 * 4 + 1][kk] = f2bf(vv.y);
          Vt[d0 + c4 * 4 + 2][kk] = f2bf(vv.z);
          Vt[d0 + c4 * 4 + 3][kk] = f2bf(vv.w);
        }
      }
      __syncthreads();
#pragma unroll
      for (int t = 0; t < 4; ++t) {
        float4v acc = {0.f, 0.f, 0.f, 0.f};
        const unsigned short* kp = &Ks[kh + t * 16 + l15][quad * 8];
        const short8v b0 = load8(kp);
        const short8v b1 = load8(kp + 32);
        acc = __builtin_amdgcn_mfma_f32_16x16x32_bf16(aq0, b0, acc, 0, 0, 0);
        acc = __builtin_amdgcn_mfma_f32_16x16x32_bf16(aq1, b1, acc, 0, 0, 0);
        const int c = kt * KTILE + kh + t * 16 + l15;
        const int bsh = ((kt2 >> 1) << 3) | ((kt2 & 1) << 2) | t;
#pragma unroll
        for (int r = 0; r < 4; ++r) {
          const int row = qs + quad * 4 + r;
          const bool msk = (mreg[r][half] >> bsh) & 1ULL;
          const float p = msk ? 0.f : __expf(acc[r] * 0.125f);
          Ps[row][kh + t * 16 + l15] = f2bf(p);         // unnormalized P for PV
          Ag[(size_t)row * SS + c] = p * inv[r];        // normalized attn out (fp32)
        }
      }
      __syncthreads();
      // PV: context[q][d] += P[q][kk] * V[kk][d]
#pragma unroll
      for (int ks = 0; ks < 4; ++ks) {
        const short8v ap = *(const short8v*)&Ps[qs + l15][ks * 32 + quad * 8];
        const short8v bv0 = *(const short8v*)&Vt[dh + l15][ks * 32 + quad * 8];
        const short8v bv1 = *(const short8v*)&Vt[dh + 16 + l15][ks * 32 + quad * 8];
        cacc0 = __builtin_amdgcn_mfma_f32_16x16x32_bf16(ap, bv0, cacc0, 0, 0, 0);
        cacc1 = __builtin_amdgcn_mfma_f32_16x16x32_bf16(ap, bv1, cacc1, 0, 0, 0);
      }
      __syncthreads();
    }
  }

  // context epilogue (normalize at the end)
#pragma unroll
  for (int r = 0; r < 4; ++r) {
    const int row = qs + quad * 4 + r;
    Cg[(size_t)row * DD + dh + l15] = cacc0[r] * inv[r];
    Cg[(size_t)row * DD + dh + 16 + l15] = cacc1[r] * inv[r];
  }
}

extern "C" void kernel_launch(void* const* d_in, const int* in_sizes, int n_in,
                              void* d_out, int out_size, void* d_ws, size_t ws_size,
                              hipStream_t stream) {
  const float* q = (const float*)d_in[0];
  const float* k = (const float*)d_in[1];
  const float* v = (const float*)d_in[2];
  const int*   m = (const int*)d_in[3];
  float* ctx  = (float*)d_out;                        // [B,S,D] first output
  float* attn = (float*)d_out + (size_t)BB * SS * DD; // [B,S,S] second output
  dim3 grid(BB * (SS / QT));  // 512 blocks
  attn_fused_kernel<<<grid, NTHREADS, 0, stream>>>(q, k, v, m, ctx, attn);
}